// Round 6
// baseline (134.399 us; speedup 1.0000x reference)
//
#include <hip/hip_runtime.h>

#define PTOT 200000
#define NB 512
#define DD 64
#define PT 256
#define NBLK ((PTOT + PT - 1) / PT)   /* 782 tiles */
#define NPAD (NBLK * PT)              /* 200192 */
#define NP3 (NBLK * 3)                /* 2346 pool keys per b */
#define NCAND 8

typedef __attribute__((ext_vector_type(4))) float f32x4;
typedef __attribute__((ext_vector_type(8))) __bf16 bf16x8;

__device__ __forceinline__ ushort f2bf(float f){
  uint u = __float_as_uint(f);
  u += 0x7FFFu + ((u >> 16) & 1u);
  return (ushort)(u >> 16);
}

__device__ __forceinline__ void ins3(uint& k0, uint& k1, uint& k2, uint key){
  uint t0 = k0 > key ? k0 : key;
  uint m0 = k0 > key ? key : k0;
  uint t1 = k1 > m0 ? k1 : m0;
  uint m1 = k1 > m0 ? m0 : k1;
  k2 = k2 > m1 ? k2 : m1;
  k1 = t1; k0 = t0;
}

// ---------------- kA: streaming centers->bf16 cn  +  target normalize ----
__global__ __launch_bounds__(256) void kA_stream(const float* __restrict__ sp,
                                                 const float* __restrict__ tf,
                                                 ushort* __restrict__ cn,
                                                 float* __restrict__ tnf,
                                                 ushort* __restrict__ tnb){
  const int tglob = blockIdx.x * 256 + threadIdx.x;
  const int s = tglob & 15;
  const int NG = NPAD + NB;
  const int gstride = (2048 * 256) / 16;
  for (int g = tglob >> 4; g < NG; g += gstride){
    f32x4 c = {0.f, 0.f, 0.f, 0.f};
    if (g < NPAD){
      if (g < PTOT){
        const float* base = sp + (size_t)g * 256 + s * 4;
        f32x4 a0 = *(const f32x4*)(base);
        f32x4 a1 = *(const f32x4*)(base + 64);
        f32x4 a2 = *(const f32x4*)(base + 128);
        f32x4 a3 = *(const f32x4*)(base + 192);
        c = ((a0 + a1) + (a2 + a3)) * 0.25f;
      }
    } else {
      c = *(const f32x4*)(tf + (g - NPAD) * 64 + s * 4);
    }
    float ss = c.x*c.x + c.y*c.y + c.z*c.z + c.w*c.w;
    ss += __shfl_xor(ss, 1, 64);
    ss += __shfl_xor(ss, 2, 64);
    ss += __shfl_xor(ss, 4, 64);
    ss += __shfl_xor(ss, 8, 64);
    float rn = 1.0f / fmaxf(sqrtf(ss), 1e-8f);
    float n0 = c.x * rn, n1 = c.y * rn, n2 = c.z * rn, n3 = c.w * rn;
    ushort4 h;
    h.x = f2bf(n0); h.y = f2bf(n1); h.z = f2bf(n2); h.w = f2bf(n3);
    if (g < NPAD){
      *(ushort4*)(cn + (size_t)g * 64 + s * 4) = h;
    } else {
      int b = g - NPAD;
      f32x4 t = {n0, n1, n2, n3};
      *(f32x4*)(tnf + b * 64 + s * 4) = t;
      *(ushort4*)(tnb + b * 64 + s * 4) = h;
    }
  }
}

// ---------------- kB: MFMA sims + per-tile top-3, MINIMAL LIVE STATE -----
// One b-tile finished at a time: live regs = bf0/bf1(8) + one key triple(3)
// + transient a0/a1/acc(12). No large per-lane arrays -> no scratch spills.
__global__ __launch_bounds__(256, 4) void kB_scan(const ushort* __restrict__ cn,
                                                  const ushort* __restrict__ tnb,
                                                  uint* __restrict__ cand){
  __shared__ __align__(16) ushort lds[PT * 64];   // 32 KB, XOR-swizzled
  const int tid = threadIdx.x;
  const int blk = blockIdx.x;
  const int wave = tid >> 6;
  const int lane = tid & 63;
  const int l15 = lane & 15;
  const int lg  = lane >> 4;

  // stage cn tile: 8 independent 16B loads/thread, swizzled LDS writes
  {
    const char* src = (const char*)(cn + (size_t)blk * PT * 64);
    #pragma unroll
    for (int k = 0; k < 8; ++k){
      int off = (k * 256 + tid) * 16;
      f32x4 v = *(const f32x4*)(src + off);
      int dst = off ^ (((off >> 7) & 7) << 4);
      *(f32x4*)((char*)lds + dst) = v;
    }
  }
  __syncthreads();

  #pragma unroll 2
  for (int bt8 = 0; bt8 < 8; ++bt8){
    const int bt = wave * 8 + bt8;
    const ushort* tp = tnb + (size_t)(bt * 16 + l15) * 64 + lg * 8;
    bf16x8 bf0 = *(const bf16x8*)(tp);
    bf16x8 bf1 = *(const bf16x8*)(tp + 32);
    uint k0 = 0, k1 = 0, k2 = 0;
    #pragma unroll 4
    for (int ps = 0; ps < 16; ++ps){
      const int p = ps * 16 + l15;
      const int base = p * 128;
      const int sw = (p & 7) << 4;
      bf16x8 a0 = *(const bf16x8*)((const char*)lds + ((base + lg * 16) ^ sw));
      bf16x8 a1 = *(const bf16x8*)((const char*)lds + ((base + 64 + lg * 16) ^ sw));
      f32x4 z = {0.f, 0.f, 0.f, 0.f};
      f32x4 acc = __builtin_amdgcn_mfma_f32_16x16x32_bf16(a0, bf0, z, 0, 0, 0);
      acc = __builtin_amdgcn_mfma_f32_16x16x32_bf16(a1, bf1, acc, 0, 0, 0);
      #pragma unroll
      for (int j = 0; j < 4; ++j){
        uint key = (__float_as_uint(fmaxf(acc[j], 0.0f)) & 0xFFFFFE00u)
                 | (uint)(ps * 16 + lg * 4 + j);
        ins3(k0, k1, k2, key);
      }
    }
    // merge the 4 lg groups sharing each b
    #pragma unroll
    for (int m = 16; m <= 32; m <<= 1){
      uint o0 = (uint)__shfl_xor((int)k0, m, 64);
      uint o1 = (uint)__shfl_xor((int)k1, m, 64);
      uint o2 = (uint)__shfl_xor((int)k2, m, 64);
      ins3(k0, k1, k2, o0); ins3(k0, k1, k2, o1); ins3(k0, k1, k2, o2);
    }
    if (lane < 16){
      int b = bt * 16 + l15;
      uint* dst = cand + ((size_t)blk * NB + b) * 3;   // [tile][b][3]
      dst[0] = k0; dst[1] = k1; dst[2] = k2;
    }
  }
}

// ---------------- kC: wave top-8 + exact rerank + softmax + fused MLP ----
__global__ __launch_bounds__(256) void kC_fuse(const uint* __restrict__ cand,
    const float* __restrict__ sp, const float* __restrict__ tnf,
    const float* __restrict__ tf,
    const float* __restrict__ W1, const float* __restrict__ b1,
    const float* __restrict__ lng, const float* __restrict__ lnb,
    const float* __restrict__ W2, const float* __restrict__ b2,
    const float* __restrict__ W3, const float* __restrict__ b3,
    float* __restrict__ out){
  __shared__ float cc[4][192];
  __shared__ float h1[4][256];
  __shared__ float h2[4][256];
  const int tid = threadIdx.x;
  const int lane = tid & 63;
  const int w = tid >> 6;
  const int rb = blockIdx.x * 4;
  const int b = rb + w;

  // per-lane top-3 (key, idx) over this b's pool (transposed layout)
  uint k0 = 0, k1 = 0, k2 = 0; int j0 = 0, j1 = 0, j2 = 0;
  for (int i = 0; i < (NP3 + 63) / 64; ++i){
    int j = lane + i * 64;
    uint k = 0;
    if (j < NP3){
      int t = j / 3, r = j - t * 3;
      k = cand[(size_t)t * (NB * 3) + b * 3 + r];
    }
    if (k > k0){ k2=k1; j2=j1; k1=k0; j1=j0; k0=k; j0=j; }
    else if (k > k1){ k2=k1; j2=j1; k1=k; j1=j; }
    else if (k > k2){ k2=k; j2=j; }
  }
  int pcand[NCAND];
  #pragma unroll
  for (int it = 0; it < NCAND; ++it){
    uint wk = k0; int wj = j0;
    #pragma unroll
    for (int m = 1; m < 64; m <<= 1){
      uint ok = (uint)__shfl_xor((int)wk, m, 64);
      int  oj = __shfl_xor(wj, m, 64);
      if (ok > wk || (ok == wk && oj > wj)){ wk = ok; wj = oj; }
    }
    pcand[it] = min((wj / 3) * PT + (int)(wk & 0x1FFu), PTOT - 1);
    if (k0 == wk && j0 == wj){ k0=k1; j0=j1; k1=k2; j1=j2; k2=0; j2=0; }
  }
  float xc[NCAND], es[NCAND];
  const float tno = tnf[b * 64 + lane];
  #pragma unroll
  for (int c = 0; c < NCAND; ++c){
    const float* base = sp + (size_t)pcand[c] * 256 + lane;
    float x = 0.25f * (base[0] + base[64] + base[128] + base[192]);
    float ss = x * x;
    float dt = x * tno;
    #pragma unroll
    for (int m = 1; m < 64; m <<= 1){
      ss += __shfl_xor(ss, m, 64);
      dt += __shfl_xor(dt, m, 64);
    }
    xc[c] = x;
    es[c] = dt / fmaxf(sqrtf(ss), 1e-8f);
  }
  float v0 = -3.0e38f, v1 = v0, v2 = v0;
  int s0 = 0, s1 = 0, s2 = 0;
  #pragma unroll
  for (int c = 0; c < NCAND; ++c){
    float v = es[c];
    if (v > v0){ v2=v1; s2=s1; v1=v0; s1=s0; v0=v; s0=c; }
    else if (v > v1){ v2=v1; s2=s1; v1=v; s1=c; }
    else if (v > v2){ v2=v; s2=c; }
  }
  float e1 = expf(v1 - v0), e2 = expf(v2 - v0);
  float inv = 1.0f / (1.0f + e1 + e2);
  float w0 = inv, w1 = e1 * inv, w2 = e2 * inv;
  float wsum = 0.f, ctop = 0.f;
  #pragma unroll
  for (int c = 0; c < NCAND; ++c){     // static indexing only (rule #20)
    float coef = (c == s0) ? w0 : (c == s1) ? w1 : (c == s2) ? w2 : 0.f;
    wsum = fmaf(xc[c], coef, wsum);
    ctop += (c == s0) ? xc[c] : 0.f;
  }
  cc[w][lane]       = wsum;
  cc[w][64 + lane]  = ctop;
  cc[w][128 + lane] = tf[b * 64 + lane];
  __syncthreads();

  // ---- MLP over the 4 rows ----
  {
    const int h = tid;
    float a0 = b1[h]; float a1 = a0, a2 = a0, a3 = a0;
    for (int k = 0; k < 192; ++k){
      float wv = W1[k * 256 + h];
      a0 = fmaf(cc[0][k], wv, a0);
      a1 = fmaf(cc[1][k], wv, a1);
      a2 = fmaf(cc[2][k], wv, a2);
      a3 = fmaf(cc[3][k], wv, a3);
    }
    h1[0][h] = a0; h1[1][h] = a1; h1[2][h] = a2; h1[3][h] = a3;
  }
  __syncthreads();
  {
    float v[4]; float s = 0.f, q = 0.f;
    #pragma unroll
    for (int j = 0; j < 4; ++j){
      v[j] = h1[w][lane + 64 * j];
      s += v[j]; q += v[j] * v[j];
    }
    #pragma unroll
    for (int m = 1; m < 64; m <<= 1){
      s += __shfl_xor(s, m, 64);
      q += __shfl_xor(q, m, 64);
    }
    float mu = s * (1.0f / 256.0f);
    float var = q * (1.0f / 256.0f) - mu * mu;
    float rs = rsqrtf(var + 1e-5f);
    #pragma unroll
    for (int j = 0; j < 4; ++j){
      int hh = lane + 64 * j;
      float y = (v[j] - mu) * rs * lng[hh] + lnb[hh];
      h1[w][hh] = fmaxf(y, 0.0f);
    }
  }
  __syncthreads();
  {
    const int h = tid;
    float a0 = b2[h]; float a1 = a0, a2 = a0, a3 = a0;
    for (int k = 0; k < 256; ++k){
      float wv = W2[k * 256 + h];
      a0 = fmaf(h1[0][k], wv, a0);
      a1 = fmaf(h1[1][k], wv, a1);
      a2 = fmaf(h1[2][k], wv, a2);
      a3 = fmaf(h1[3][k], wv, a3);
    }
    h2[0][h] = fmaxf(a0, 0.f); h2[1][h] = fmaxf(a1, 0.f);
    h2[2][h] = fmaxf(a2, 0.f); h2[3][h] = fmaxf(a3, 0.f);
  }
  __syncthreads();
  {
    const int d = tid & 63, q = tid >> 6;
    float a = b3[d];
    for (int k = 0; k < 256; ++k)
      a = fmaf(h2[q][k], W3[k * 64 + d], a);
    out[(size_t)(rb + q) * 64 + d] = a;
  }
}

extern "C" void kernel_launch(void* const* d_in, const int* in_sizes, int n_in,
                              void* d_out, int out_size, void* d_ws, size_t ws_size,
                              hipStream_t stream){
  const float* tf = (const float*)d_in[0];
  const float* sp = (const float*)d_in[1];
  const float* W1 = (const float*)d_in[2];
  const float* b1 = (const float*)d_in[3];
  const float* lng = (const float*)d_in[4];
  const float* lnb = (const float*)d_in[5];
  const float* W2 = (const float*)d_in[6];
  const float* b2 = (const float*)d_in[7];
  const float* W3 = (const float*)d_in[8];
  const float* b3 = (const float*)d_in[9];
  float* out = (float*)d_out;

  char* ws = (char*)d_ws;
  const size_t off_tnb  = 0;                       // 64 KB
  const size_t off_tnf  = 65536;                   // 128 KB
  const size_t off_cn   = 65536 + 131072;          // 25.6 MB
  const size_t cn_bytes = (size_t)NPAD * 64 * 2;
  const size_t off_cand = off_cn + cn_bytes;       // 4.8 MB  [tile][b][3]
  const size_t need = off_cand + (size_t)NBLK * NB * 3 * 4;
  if (ws_size < need) return;

  ushort* tnb = (ushort*)(ws + off_tnb);
  float*  tnf = (float*)(ws + off_tnf);
  ushort* cnb = (ushort*)(ws + off_cn);
  uint*   cand = (uint*)(ws + off_cand);

  kA_stream<<<2048, 256, 0, stream>>>(sp, tf, cnb, tnf, tnb);
  kB_scan<<<NBLK, 256, 0, stream>>>(cnb, tnb, cand);
  kC_fuse<<<NB / 4, 256, 0, stream>>>(cand, sp, tnf, tf,
                                      W1, b1, lng, lnb, W2, b2, W3, b3, out);
}

// Round 7
// 132.365 us; speedup vs baseline: 1.0154x; 1.0154x over previous
//
#include <hip/hip_runtime.h>

#define PTOT 200000
#define NB 512
#define DD 64
#define PT 256
#define NBLK ((PTOT + PT - 1) / PT)   /* 782 tiles */
#define NPAD (NBLK * PT)              /* 200192 */
#define NP3 (NBLK * 3)                /* 2346 pool keys per b */
#define NCAND 8

typedef __attribute__((ext_vector_type(4))) float f32x4;
typedef __attribute__((ext_vector_type(8))) __bf16 bf16x8;

__device__ __forceinline__ ushort f2bf(float f){
  uint u = __float_as_uint(f);
  u += 0x7FFFu + ((u >> 16) & 1u);
  return (ushort)(u >> 16);
}

__device__ __forceinline__ void ins3(uint& k0, uint& k1, uint& k2, uint key){
  uint t0 = k0 > key ? k0 : key;
  uint m0 = k0 > key ? key : k0;
  uint t1 = k1 > m0 ? k1 : m0;
  uint m1 = k1 > m0 ? m0 : k1;
  k2 = k2 > m1 ? k2 : m1;
  k1 = t1; k0 = t0;
}

// ---------------- kA: BW-saturating centers + target normalize -----------
// 4 threads per row; each thread owns 16 d's -> 16 INDEPENDENT 16B loads in
// flight (256B/lane, Little's-law fix), local mean+ss, 2-step shfl across
// the row's 4 lanes only. Rows >= NPAD are target rows (v[1..3]=v[0]).
__global__ __launch_bounds__(256) void kA_stream(const float* __restrict__ sp,
                                                 const float* __restrict__ tf,
                                                 ushort* __restrict__ cn,
                                                 float* __restrict__ tnf,
                                                 ushort* __restrict__ tnb){
  const int gid = blockIdx.x * 256 + threadIdx.x;
  const int row = gid >> 2;
  const int q = gid & 3;
  const bool istgt = row >= NPAD;

  f32x4 v[4][4];
  if (!istgt){
    if (row < PTOT){
      const float* base = sp + (size_t)row * 256 + q * 16;
      #pragma unroll
      for (int t = 0; t < 4; ++t){
        #pragma unroll
        for (int j = 0; j < 4; ++j)
          v[t][j] = *(const f32x4*)(base + t * 64 + j * 4);
      }
    } else {
      #pragma unroll
      for (int t = 0; t < 4; ++t)
        #pragma unroll
        for (int j = 0; j < 4; ++j)
          v[t][j] = (f32x4){0.f, 0.f, 0.f, 0.f};
    }
  } else {
    const float* base = tf + (size_t)(row - NPAD) * 64 + q * 16;
    #pragma unroll
    for (int j = 0; j < 4; ++j){
      v[0][j] = *(const f32x4*)(base + j * 4);
      v[1][j] = v[0][j]; v[2][j] = v[0][j]; v[3][j] = v[0][j];
    }
  }

  f32x4 c[4];
  float ss = 0.f;
  #pragma unroll
  for (int j = 0; j < 4; ++j){
    c[j] = ((v[0][j] + v[1][j]) + (v[2][j] + v[3][j])) * 0.25f;
    ss += c[j].x*c[j].x + c[j].y*c[j].y + c[j].z*c[j].z + c[j].w*c[j].w;
  }
  ss += __shfl_xor(ss, 1, 64);
  ss += __shfl_xor(ss, 2, 64);
  float rn = 1.0f / fmaxf(sqrtf(ss), 1e-8f);

  uint u[8];
  #pragma unroll
  for (int j = 0; j < 4; ++j){
    u[2*j]   = (uint)f2bf(c[j].x * rn) | ((uint)f2bf(c[j].y * rn) << 16);
    u[2*j+1] = (uint)f2bf(c[j].z * rn) | ((uint)f2bf(c[j].w * rn) << 16);
  }
  if (!istgt){
    uint4* dst = (uint4*)(cn + (size_t)row * 64 + q * 16);
    dst[0] = make_uint4(u[0], u[1], u[2], u[3]);
    dst[1] = make_uint4(u[4], u[5], u[6], u[7]);
  } else {
    const int b = row - NPAD;
    float* fd = tnf + (size_t)b * 64 + q * 16;
    #pragma unroll
    for (int j = 0; j < 4; ++j)
      *(f32x4*)(fd + j * 4) = c[j] * rn;
    uint4* hd = (uint4*)(tnb + (size_t)b * 64 + q * 16);
    hd[0] = make_uint4(u[0], u[1], u[2], u[3]);
    hd[1] = make_uint4(u[4], u[5], u[6], u[7]);
  }
}

// ---------------- kB: MFMA sims + per-tile top-3 (R6 structure) ----------
__global__ __launch_bounds__(256, 4) void kB_scan(const ushort* __restrict__ cn,
                                                  const ushort* __restrict__ tnb,
                                                  uint* __restrict__ cand){
  __shared__ __align__(16) ushort lds[PT * 64];   // 32 KB, XOR-swizzled
  const int tid = threadIdx.x;
  const int blk = blockIdx.x;
  const int wave = tid >> 6;
  const int lane = tid & 63;
  const int l15 = lane & 15;
  const int lg  = lane >> 4;

  {
    const char* src = (const char*)(cn + (size_t)blk * PT * 64);
    #pragma unroll
    for (int k = 0; k < 8; ++k){
      int off = (k * 256 + tid) * 16;
      f32x4 v = *(const f32x4*)(src + off);
      int dst = off ^ (((off >> 7) & 7) << 4);
      *(f32x4*)((char*)lds + dst) = v;
    }
  }
  __syncthreads();

  #pragma unroll 2
  for (int bt8 = 0; bt8 < 8; ++bt8){
    const int bt = wave * 8 + bt8;
    const ushort* tp = tnb + (size_t)(bt * 16 + l15) * 64 + lg * 8;
    bf16x8 bf0 = *(const bf16x8*)(tp);
    bf16x8 bf1 = *(const bf16x8*)(tp + 32);
    uint k0 = 0, k1 = 0, k2 = 0;
    #pragma unroll 4
    for (int ps = 0; ps < 16; ++ps){
      const int p = ps * 16 + l15;
      const int base = p * 128;
      const int sw = (p & 7) << 4;
      bf16x8 a0 = *(const bf16x8*)((const char*)lds + ((base + lg * 16) ^ sw));
      bf16x8 a1 = *(const bf16x8*)((const char*)lds + ((base + 64 + lg * 16) ^ sw));
      f32x4 z = {0.f, 0.f, 0.f, 0.f};
      f32x4 acc = __builtin_amdgcn_mfma_f32_16x16x32_bf16(a0, bf0, z, 0, 0, 0);
      acc = __builtin_amdgcn_mfma_f32_16x16x32_bf16(a1, bf1, acc, 0, 0, 0);
      #pragma unroll
      for (int j = 0; j < 4; ++j){
        uint key = (__float_as_uint(fmaxf(acc[j], 0.0f)) & 0xFFFFFE00u)
                 | (uint)(ps * 16 + lg * 4 + j);
        ins3(k0, k1, k2, key);
      }
    }
    #pragma unroll
    for (int m = 16; m <= 32; m <<= 1){
      uint o0 = (uint)__shfl_xor((int)k0, m, 64);
      uint o1 = (uint)__shfl_xor((int)k1, m, 64);
      uint o2 = (uint)__shfl_xor((int)k2, m, 64);
      ins3(k0, k1, k2, o0); ins3(k0, k1, k2, o1); ins3(k0, k1, k2, o2);
    }
    if (lane < 16){
      int b = bt * 16 + l15;
      uint* dst = cand + ((size_t)blk * NB + b) * 3;   // [tile][b][3]
      dst[0] = k0; dst[1] = k1; dst[2] = k2;
    }
  }
}

// ---------------- kC: wave top-8 + exact rerank + softmax + fused MLP ----
__global__ __launch_bounds__(256) void kC_fuse(const uint* __restrict__ cand,
    const float* __restrict__ sp, const float* __restrict__ tnf,
    const float* __restrict__ tf,
    const float* __restrict__ W1, const float* __restrict__ b1,
    const float* __restrict__ lng, const float* __restrict__ lnb,
    const float* __restrict__ W2, const float* __restrict__ b2,
    const float* __restrict__ W3, const float* __restrict__ b3,
    float* __restrict__ out){
  __shared__ float cc[4][192];
  __shared__ float h1[4][256];
  __shared__ float h2[4][256];
  const int tid = threadIdx.x;
  const int lane = tid & 63;
  const int w = tid >> 6;
  const int rb = blockIdx.x * 4;
  const int b = rb + w;

  uint k0 = 0, k1 = 0, k2 = 0; int j0 = 0, j1 = 0, j2 = 0;
  for (int i = 0; i < (NP3 + 63) / 64; ++i){
    int j = lane + i * 64;
    uint k = 0;
    if (j < NP3){
      int t = j / 3, r = j - t * 3;
      k = cand[(size_t)t * (NB * 3) + b * 3 + r];
    }
    if (k > k0){ k2=k1; j2=j1; k1=k0; j1=j0; k0=k; j0=j; }
    else if (k > k1){ k2=k1; j2=j1; k1=k; j1=j; }
    else if (k > k2){ k2=k; j2=j; }
  }
  int pcand[NCAND];
  #pragma unroll
  for (int it = 0; it < NCAND; ++it){
    uint wk = k0; int wj = j0;
    #pragma unroll
    for (int m = 1; m < 64; m <<= 1){
      uint ok = (uint)__shfl_xor((int)wk, m, 64);
      int  oj = __shfl_xor(wj, m, 64);
      if (ok > wk || (ok == wk && oj > wj)){ wk = ok; wj = oj; }
    }
    pcand[it] = min((wj / 3) * PT + (int)(wk & 0x1FFu), PTOT - 1);
    if (k0 == wk && j0 == wj){ k0=k1; j0=j1; k1=k2; j1=j2; k2=0; j2=0; }
  }
  float xc[NCAND], es[NCAND];
  const float tno = tnf[b * 64 + lane];
  #pragma unroll
  for (int c = 0; c < NCAND; ++c){
    const float* base = sp + (size_t)pcand[c] * 256 + lane;
    float x = 0.25f * (base[0] + base[64] + base[128] + base[192]);
    float ss = x * x;
    float dt = x * tno;
    #pragma unroll
    for (int m = 1; m < 64; m <<= 1){
      ss += __shfl_xor(ss, m, 64);
      dt += __shfl_xor(dt, m, 64);
    }
    xc[c] = x;
    es[c] = dt / fmaxf(sqrtf(ss), 1e-8f);
  }
  float v0 = -3.0e38f, v1 = v0, v2 = v0;
  int s0 = 0, s1 = 0, s2 = 0;
  #pragma unroll
  for (int c = 0; c < NCAND; ++c){
    float v = es[c];
    if (v > v0){ v2=v1; s2=s1; v1=v0; s1=s0; v0=v; s0=c; }
    else if (v > v1){ v2=v1; s2=s1; v1=v; s1=c; }
    else if (v > v2){ v2=v; s2=c; }
  }
  float e1 = expf(v1 - v0), e2 = expf(v2 - v0);
  float inv = 1.0f / (1.0f + e1 + e2);
  float w0 = inv, w1 = e1 * inv, w2 = e2 * inv;
  float wsum = 0.f, ctop = 0.f;
  #pragma unroll
  for (int c = 0; c < NCAND; ++c){     // static indexing only (rule #20)
    float coef = (c == s0) ? w0 : (c == s1) ? w1 : (c == s2) ? w2 : 0.f;
    wsum = fmaf(xc[c], coef, wsum);
    ctop += (c == s0) ? xc[c] : 0.f;
  }
  cc[w][lane]       = wsum;
  cc[w][64 + lane]  = ctop;
  cc[w][128 + lane] = tf[b * 64 + lane];
  __syncthreads();

  {
    const int h = tid;
    float a0 = b1[h]; float a1 = a0, a2 = a0, a3 = a0;
    for (int k = 0; k < 192; ++k){
      float wv = W1[k * 256 + h];
      a0 = fmaf(cc[0][k], wv, a0);
      a1 = fmaf(cc[1][k], wv, a1);
      a2 = fmaf(cc[2][k], wv, a2);
      a3 = fmaf(cc[3][k], wv, a3);
    }
    h1[0][h] = a0; h1[1][h] = a1; h1[2][h] = a2; h1[3][h] = a3;
  }
  __syncthreads();
  {
    float v[4]; float s = 0.f, q = 0.f;
    #pragma unroll
    for (int j = 0; j < 4; ++j){
      v[j] = h1[w][lane + 64 * j];
      s += v[j]; q += v[j] * v[j];
    }
    #pragma unroll
    for (int m = 1; m < 64; m <<= 1){
      s += __shfl_xor(s, m, 64);
      q += __shfl_xor(q, m, 64);
    }
    float mu = s * (1.0f / 256.0f);
    float var = q * (1.0f / 256.0f) - mu * mu;
    float rs = rsqrtf(var + 1e-5f);
    #pragma unroll
    for (int j = 0; j < 4; ++j){
      int hh = lane + 64 * j;
      float y = (v[j] - mu) * rs * lng[hh] + lnb[hh];
      h1[w][hh] = fmaxf(y, 0.0f);
    }
  }
  __syncthreads();
  {
    const int h = tid;
    float a0 = b2[h]; float a1 = a0, a2 = a0, a3 = a0;
    for (int k = 0; k < 256; ++k){
      float wv = W2[k * 256 + h];
      a0 = fmaf(h1[0][k], wv, a0);
      a1 = fmaf(h1[1][k], wv, a1);
      a2 = fmaf(h1[2][k], wv, a2);
      a3 = fmaf(h1[3][k], wv, a3);
    }
    h2[0][h] = fmaxf(a0, 0.f); h2[1][h] = fmaxf(a1, 0.f);
    h2[2][h] = fmaxf(a2, 0.f); h2[3][h] = fmaxf(a3, 0.f);
  }
  __syncthreads();
  {
    const int d = tid & 63, q = tid >> 6;
    float a = b3[d];
    for (int k = 0; k < 256; ++k)
      a = fmaf(h2[q][k], W3[k * 64 + d], a);
    out[(size_t)(rb + q) * 64 + d] = a;
  }
}

extern "C" void kernel_launch(void* const* d_in, const int* in_sizes, int n_in,
                              void* d_out, int out_size, void* d_ws, size_t ws_size,
                              hipStream_t stream){
  const float* tf = (const float*)d_in[0];
  const float* sp = (const float*)d_in[1];
  const float* W1 = (const float*)d_in[2];
  const float* b1 = (const float*)d_in[3];
  const float* lng = (const float*)d_in[4];
  const float* lnb = (const float*)d_in[5];
  const float* W2 = (const float*)d_in[6];
  const float* b2 = (const float*)d_in[7];
  const float* W3 = (const float*)d_in[8];
  const float* b3 = (const float*)d_in[9];
  float* out = (float*)d_out;

  char* ws = (char*)d_ws;
  const size_t off_tnb  = 0;                       // 64 KB
  const size_t off_tnf  = 65536;                   // 128 KB
  const size_t off_cn   = 65536 + 131072;          // 25.6 MB
  const size_t cn_bytes = (size_t)NPAD * 64 * 2;
  const size_t off_cand = off_cn + cn_bytes;       // 4.8 MB  [tile][b][3]
  const size_t need = off_cand + (size_t)NBLK * NB * 3 * 4;
  if (ws_size < need) return;

  ushort* tnb = (ushort*)(ws + off_tnb);
  float*  tnf = (float*)(ws + off_tnf);
  ushort* cnb = (ushort*)(ws + off_cn);
  uint*   cand = (uint*)(ws + off_cand);

  // rows: NPAD centers + NB targets, 4 threads each
  const int nthreads = (NPAD + NB) * 4;            // 802816 = 3136 * 256
  kA_stream<<<nthreads / 256, 256, 0, stream>>>(sp, tf, cnb, tnf, tnb);
  kB_scan<<<NBLK, 256, 0, stream>>>(cnb, tnb, cand);
  kC_fuse<<<NB / 4, 256, 0, stream>>>(cand, sp, tnf, tf,
                                      W1, b1, lng, lnb, W2, b2, W3, b3, out);
}

// Round 8
// 123.404 us; speedup vs baseline: 1.0891x; 1.0726x over previous
//
#include <hip/hip_runtime.h>

#define PTOT 200000
#define NB 512
#define DD 64
#define PT 256
#define NBLK ((PTOT + PT - 1) / PT)   /* 782 tiles */
#define NP3 (NBLK * 3)                /* 2346 pool keys per b */
#define NCAND 8

typedef __attribute__((ext_vector_type(4))) float f32x4;
typedef __attribute__((ext_vector_type(8))) __bf16 bf16x8;

__device__ __forceinline__ ushort f2bf(float f){
  uint u = __float_as_uint(f);
  u += 0x7FFFu + ((u >> 16) & 1u);
  return (ushort)(u >> 16);
}

__device__ __forceinline__ void ins3(uint& k0, uint& k1, uint& k2, uint key){
  uint t0 = k0 > key ? k0 : key;
  uint m0 = k0 > key ? key : k0;
  uint t1 = k1 > m0 ? k1 : m0;
  uint m1 = k1 > m0 ? m0 : k1;
  k2 = k2 > m1 ? k2 : m1;
  k1 = t1; k0 = t0;
}

// ---------------- kT: normalize target rows -> f32 + bf16 ----------------
__global__ __launch_bounds__(64) void kT_tn(const float* __restrict__ tf,
                                            float* __restrict__ tnf,
                                            ushort* __restrict__ tnb){
  int b = blockIdx.x, d = threadIdx.x;
  float v = tf[b * DD + d];
  float ss = v * v;
  #pragma unroll
  for (int m = 1; m < 64; m <<= 1) ss += __shfl_xor(ss, m, 64);
  float rn = 1.0f / fmaxf(sqrtf(ss), 1e-8f);
  float t = v * rn;
  tnf[b * DD + d] = t;
  tnb[b * DD + d] = f2bf(t);
}

// ---------------- kS: fused stage(sp->LDS) + MFMA scan + top-3 -----------
// Stage: 4 threads/row, 16 INDEPENDENT f32x4 loads each (no dependent
// chain), in-thread T-mean, 2-shfl norm, swizzled LDS write. Scan: R6's
// minimal-live-state per-bt8 structure. cand transposed [tile][b][3].
__global__ __launch_bounds__(256, 4) void kS_scan(const float* __restrict__ sp,
                                                  const ushort* __restrict__ tnb,
                                                  uint* __restrict__ cand){
  __shared__ __align__(16) ushort lds[PT * 64];   // 32 KB, XOR-swizzled
  const int tid = threadIdx.x;
  const int blk = blockIdx.x;
  const int q  = tid & 3;        // d-quarter (16 d's)
  const int pr = tid >> 2;       // 64 rows per pass
  const int wave = tid >> 6;
  const int lane = tid & 63;
  const int l15 = lane & 15;
  const int lg  = lane >> 4;

  // ---- stage: 4 passes x 64 rows; 16 loads in flight per thread ----
  #pragma unroll
  for (int pass = 0; pass < 4; ++pass){
    const int pl = pass * 64 + pr;
    const int g = blk * PT + pl;
    f32x4 v[4][4];
    if (g < PTOT){
      const float* base = sp + (size_t)g * 256 + q * 16;
      #pragma unroll
      for (int t = 0; t < 4; ++t)
        #pragma unroll
        for (int j = 0; j < 4; ++j)
          v[t][j] = *(const f32x4*)(base + t * 64 + j * 4);
    } else {
      #pragma unroll
      for (int t = 0; t < 4; ++t)
        #pragma unroll
        for (int j = 0; j < 4; ++j)
          v[t][j] = (f32x4){0.f, 0.f, 0.f, 0.f};
    }
    f32x4 c[4];
    float ss = 0.f;
    #pragma unroll
    for (int j = 0; j < 4; ++j){
      c[j] = ((v[0][j] + v[1][j]) + (v[2][j] + v[3][j])) * 0.25f;
      ss += c[j].x*c[j].x + c[j].y*c[j].y + c[j].z*c[j].z + c[j].w*c[j].w;
    }
    ss += __shfl_xor(ss, 1, 64);
    ss += __shfl_xor(ss, 2, 64);
    float rn = 1.0f / fmaxf(sqrtf(ss), 1e-8f);
    uint u[8];
    #pragma unroll
    for (int j = 0; j < 4; ++j){
      u[2*j]   = (uint)f2bf(c[j].x * rn) | ((uint)f2bf(c[j].y * rn) << 16);
      u[2*j+1] = (uint)f2bf(c[j].z * rn) | ((uint)f2bf(c[j].w * rn) << 16);
    }
    const int rowb = pl * 128 + q * 32;
    const int sw = (pl & 7) << 4;
    *(uint4*)((char*)lds + ((rowb)      ^ sw)) = make_uint4(u[0], u[1], u[2], u[3]);
    *(uint4*)((char*)lds + ((rowb + 16) ^ sw)) = make_uint4(u[4], u[5], u[6], u[7]);
  }
  __syncthreads();

  // ---- scan: per-lane top-3 over 256 p's for this wave's 8 b-tiles ----
  #pragma unroll 2
  for (int bt8 = 0; bt8 < 8; ++bt8){
    const int bt = wave * 8 + bt8;
    const ushort* tp = tnb + (size_t)(bt * 16 + l15) * 64 + lg * 8;
    bf16x8 bf0 = *(const bf16x8*)(tp);
    bf16x8 bf1 = *(const bf16x8*)(tp + 32);
    uint k0 = 0, k1 = 0, k2 = 0;
    #pragma unroll 4
    for (int ps = 0; ps < 16; ++ps){
      const int p = ps * 16 + l15;
      const int base = p * 128;
      const int sw = (p & 7) << 4;
      bf16x8 a0 = *(const bf16x8*)((const char*)lds + ((base + lg * 16) ^ sw));
      bf16x8 a1 = *(const bf16x8*)((const char*)lds + ((base + 64 + lg * 16) ^ sw));
      f32x4 z = {0.f, 0.f, 0.f, 0.f};
      f32x4 acc = __builtin_amdgcn_mfma_f32_16x16x32_bf16(a0, bf0, z, 0, 0, 0);
      acc = __builtin_amdgcn_mfma_f32_16x16x32_bf16(a1, bf1, acc, 0, 0, 0);
      #pragma unroll
      for (int j = 0; j < 4; ++j){
        uint key = (__float_as_uint(fmaxf(acc[j], 0.0f)) & 0xFFFFFE00u)
                 | (uint)(ps * 16 + lg * 4 + j);
        ins3(k0, k1, k2, key);
      }
    }
    #pragma unroll
    for (int m = 16; m <= 32; m <<= 1){
      uint o0 = (uint)__shfl_xor((int)k0, m, 64);
      uint o1 = (uint)__shfl_xor((int)k1, m, 64);
      uint o2 = (uint)__shfl_xor((int)k2, m, 64);
      ins3(k0, k1, k2, o0); ins3(k0, k1, k2, o1); ins3(k0, k1, k2, o2);
    }
    if (lane < 16){
      int b = bt * 16 + l15;
      uint* dst = cand + ((size_t)blk * NB + b) * 3;   // [tile][b][3]
      dst[0] = k0; dst[1] = k1; dst[2] = k2;
    }
  }
}

// ---------------- kC: wave top-8 + exact rerank + softmax + fused MLP ----
__global__ __launch_bounds__(256) void kC_fuse(const uint* __restrict__ cand,
    const float* __restrict__ sp, const float* __restrict__ tnf,
    const float* __restrict__ tf,
    const float* __restrict__ W1, const float* __restrict__ b1,
    const float* __restrict__ lng, const float* __restrict__ lnb,
    const float* __restrict__ W2, const float* __restrict__ b2,
    const float* __restrict__ W3, const float* __restrict__ b3,
    float* __restrict__ out){
  __shared__ float cc[4][192];
  __shared__ float h1[4][256];
  __shared__ float h2[4][256];
  const int tid = threadIdx.x;
  const int lane = tid & 63;
  const int w = tid >> 6;
  const int rb = blockIdx.x * 4;
  const int b = rb + w;

  uint k0 = 0, k1 = 0, k2 = 0; int j0 = 0, j1 = 0, j2 = 0;
  for (int i = 0; i < (NP3 + 63) / 64; ++i){
    int j = lane + i * 64;
    uint k = 0;
    if (j < NP3){
      int t = j / 3, r = j - t * 3;
      k = cand[(size_t)t * (NB * 3) + b * 3 + r];
    }
    if (k > k0){ k2=k1; j2=j1; k1=k0; j1=j0; k0=k; j0=j; }
    else if (k > k1){ k2=k1; j2=j1; k1=k; j1=j; }
    else if (k > k2){ k2=k; j2=j; }
  }
  int pcand[NCAND];
  #pragma unroll
  for (int it = 0; it < NCAND; ++it){
    uint wk = k0; int wj = j0;
    #pragma unroll
    for (int m = 1; m < 64; m <<= 1){
      uint ok = (uint)__shfl_xor((int)wk, m, 64);
      int  oj = __shfl_xor(wj, m, 64);
      if (ok > wk || (ok == wk && oj > wj)){ wk = ok; wj = oj; }
    }
    pcand[it] = min((wj / 3) * PT + (int)(wk & 0x1FFu), PTOT - 1);
    if (k0 == wk && j0 == wj){ k0=k1; j0=j1; k1=k2; j1=j2; k2=0; j2=0; }
  }
  float xc[NCAND], es[NCAND];
  const float tno = tnf[b * 64 + lane];
  #pragma unroll
  for (int c = 0; c < NCAND; ++c){
    const float* base = sp + (size_t)pcand[c] * 256 + lane;
    float x = 0.25f * (base[0] + base[64] + base[128] + base[192]);
    float ss = x * x;
    float dt = x * tno;
    #pragma unroll
    for (int m = 1; m < 64; m <<= 1){
      ss += __shfl_xor(ss, m, 64);
      dt += __shfl_xor(dt, m, 64);
    }
    xc[c] = x;
    es[c] = dt / fmaxf(sqrtf(ss), 1e-8f);
  }
  float v0 = -3.0e38f, v1 = v0, v2 = v0;
  int s0 = 0, s1 = 0, s2 = 0;
  #pragma unroll
  for (int c = 0; c < NCAND; ++c){
    float v = es[c];
    if (v > v0){ v2=v1; s2=s1; v1=v0; s1=s0; v0=v; s0=c; }
    else if (v > v1){ v2=v1; s2=s1; v1=v; s1=c; }
    else if (v > v2){ v2=v; s2=c; }
  }
  float e1 = expf(v1 - v0), e2 = expf(v2 - v0);
  float inv = 1.0f / (1.0f + e1 + e2);
  float w0 = inv, w1 = e1 * inv, w2 = e2 * inv;
  float wsum = 0.f, ctop = 0.f;
  #pragma unroll
  for (int c = 0; c < NCAND; ++c){     // static indexing only (rule #20)
    float coef = (c == s0) ? w0 : (c == s1) ? w1 : (c == s2) ? w2 : 0.f;
    wsum = fmaf(xc[c], coef, wsum);
    ctop += (c == s0) ? xc[c] : 0.f;
  }
  cc[w][lane]       = wsum;
  cc[w][64 + lane]  = ctop;
  cc[w][128 + lane] = tf[b * 64 + lane];
  __syncthreads();

  {
    const int h = tid;
    float a0 = b1[h]; float a1 = a0, a2 = a0, a3 = a0;
    for (int k = 0; k < 192; ++k){
      float wv = W1[k * 256 + h];
      a0 = fmaf(cc[0][k], wv, a0);
      a1 = fmaf(cc[1][k], wv, a1);
      a2 = fmaf(cc[2][k], wv, a2);
      a3 = fmaf(cc[3][k], wv, a3);
    }
    h1[0][h] = a0; h1[1][h] = a1; h1[2][h] = a2; h1[3][h] = a3;
  }
  __syncthreads();
  {
    float v[4]; float s = 0.f, q = 0.f;
    #pragma unroll
    for (int j = 0; j < 4; ++j){
      v[j] = h1[w][lane + 64 * j];
      s += v[j]; q += v[j] * v[j];
    }
    #pragma unroll
    for (int m = 1; m < 64; m <<= 1){
      s += __shfl_xor(s, m, 64);
      q += __shfl_xor(q, m, 64);
    }
    float mu = s * (1.0f / 256.0f);
    float var = q * (1.0f / 256.0f) - mu * mu;
    float rs = rsqrtf(var + 1e-5f);
    #pragma unroll
    for (int j = 0; j < 4; ++j){
      int hh = lane + 64 * j;
      float y = (v[j] - mu) * rs * lng[hh] + lnb[hh];
      h1[w][hh] = fmaxf(y, 0.0f);
    }
  }
  __syncthreads();
  {
    const int h = tid;
    float a0 = b2[h]; float a1 = a0, a2 = a0, a3 = a0;
    for (int k = 0; k < 256; ++k){
      float wv = W2[k * 256 + h];
      a0 = fmaf(h1[0][k], wv, a0);
      a1 = fmaf(h1[1][k], wv, a1);
      a2 = fmaf(h1[2][k], wv, a2);
      a3 = fmaf(h1[3][k], wv, a3);
    }
    h2[0][h] = fmaxf(a0, 0.f); h2[1][h] = fmaxf(a1, 0.f);
    h2[2][h] = fmaxf(a2, 0.f); h2[3][h] = fmaxf(a3, 0.f);
  }
  __syncthreads();
  {
    const int d = tid & 63, q = tid >> 6;
    float a = b3[d];
    for (int k = 0; k < 256; ++k)
      a = fmaf(h2[q][k], W3[k * 64 + d], a);
    out[(size_t)(rb + q) * 64 + d] = a;
  }
}

extern "C" void kernel_launch(void* const* d_in, const int* in_sizes, int n_in,
                              void* d_out, int out_size, void* d_ws, size_t ws_size,
                              hipStream_t stream){
  const float* tf = (const float*)d_in[0];
  const float* sp = (const float*)d_in[1];
  const float* W1 = (const float*)d_in[2];
  const float* b1 = (const float*)d_in[3];
  const float* lng = (const float*)d_in[4];
  const float* lnb = (const float*)d_in[5];
  const float* W2 = (const float*)d_in[6];
  const float* b2 = (const float*)d_in[7];
  const float* W3 = (const float*)d_in[8];
  const float* b3 = (const float*)d_in[9];
  float* out = (float*)d_out;

  char* ws = (char*)d_ws;
  const size_t off_tnb  = 0;                       // 64 KB
  const size_t off_tnf  = 65536;                   // 128 KB
  const size_t off_cand = 65536 + 131072;          // 4.8 MB  [tile][b][3]
  const size_t need = off_cand + (size_t)NBLK * NB * 3 * 4;
  if (ws_size < need) return;

  ushort* tnb = (ushort*)(ws + off_tnb);
  float*  tnf = (float*)(ws + off_tnf);
  uint*   cand = (uint*)(ws + off_cand);

  kT_tn<<<NB, 64, 0, stream>>>(tf, tnf, tnb);
  kS_scan<<<NBLK, 256, 0, stream>>>(sp, tnb, cand);
  kC_fuse<<<NB / 4, 256, 0, stream>>>(cand, sp, tnf, tf,
                                      W1, b1, lng, lnb, W2, b2, W3, b3, out);
}